// Round 2
// baseline (76.055 us; speedup 1.0000x reference)
//
#include <hip/hip_runtime.h>

// PositionalEncoding: out[b,s,d] = x[b,s,d] + (positions[b,s] >= 0 ? pe[positions[b,s], d] : 0)
// B=256, S=365, D=512, fp32. Memory-bound streaming add with gathered PE rows.
//
// D/4 = 128 float4 per row -> row = i >> 7, d4 = i & 127 (no int divide).
// pe (747 KB) and positions (373 KB) are L2/L3-resident; HBM traffic ~= x + out.

__global__ void PositionalEncoding_80659485819003_kernel(
    const float4* __restrict__ x,
    const int*    __restrict__ positions,
    const float4* __restrict__ pe,
    float4*       __restrict__ out,
    int n4)
{
    const int stride = gridDim.x * blockDim.x;
    for (int i = blockIdx.x * blockDim.x + threadIdx.x; i < n4; i += stride) {
        const int row = i >> 7;      // which (b,s) row; D/4 == 128
        const int d4  = i & 127;     // float4 index within the row
        float4 v = x[i];
        const int pos = positions[row];
        if (pos >= 0) {
            const float4 p = pe[(pos << 7) + d4];
            v.x += p.x; v.y += p.y; v.z += p.z; v.w += p.w;
        }
        out[i] = v;
    }
}

extern "C" void kernel_launch(void* const* d_in, const int* in_sizes, int n_in,
                              void* d_out, int out_size, void* d_ws, size_t ws_size,
                              hipStream_t stream)
{
    const float4* x         = (const float4*)d_in[0];
    const int*    positions = (const int*)d_in[1];
    const float4* pe        = (const float4*)d_in[2];
    float4*       out       = (float4*)d_out;

    const int n4 = out_size / 4;           // 47,841,280 floats -> 11,960,320 float4
    const int block = 256;
    int grid = (n4 + block - 1) / block;
    if (grid > 2048) grid = 2048;          // 8 blocks/CU x 256 CU, grid-stride the rest

    PositionalEncoding_80659485819003_kernel<<<grid, block, 0, stream>>>(
        x, positions, pe, out, n4);
}